// Round 13
// baseline (308.946 us; speedup 1.0000x reference)
//
#include <hip/hip_runtime.h>
#include <stdint.h>

#define NROWS 131072
#define DDIM  64
#define KCB   1024
#define BM    64           // rows per block (4 waves x 16)
#define XPAD  68           // padded LDS row stride (floats)

typedef short bf16x8 __attribute__((ext_vector_type(8)));
typedef float f32x4  __attribute__((ext_vector_type(4)));

__device__ __forceinline__ unsigned short f2bf(float f) {
    unsigned int u = __float_as_uint(f);
    u += 0x7FFFu + ((u >> 16) & 1u);
    return (unsigned short)(u >> 16);
}
__device__ __forceinline__ float bf2f(unsigned short h) {
    return __uint_as_float(((unsigned int)h) << 16);
}

// ---- pre-kernel: codebook -> bf16 hi/lo planes of (-2*c) + ||c||^2 (fp32) ----
__global__ __launch_bounds__(256)
void convert_cb(const float* __restrict__ cb,
                unsigned short* __restrict__ mh,
                unsigned short* __restrict__ ml,
                float* __restrict__ csq) {
    const int t    = blockIdx.x * 256 + threadIdx.x;   // 0..4095
    const int row  = t >> 2;
    const int part = t & 3;
    const float4* src = (const float4*)(cb + (size_t)row * DDIM + part * 16);

    unsigned short hb[16], lb[16];
    float s = 0.f;
#pragma unroll
    for (int q = 0; q < 4; ++q) {
        float4 v = src[q];
        float c, m; unsigned short h;
        c = v.x; s = fmaf(c, c, s); m = -2.f * c; h = f2bf(m);
        hb[q*4+0] = h; lb[q*4+0] = f2bf(m - bf2f(h));
        c = v.y; s = fmaf(c, c, s); m = -2.f * c; h = f2bf(m);
        hb[q*4+1] = h; lb[q*4+1] = f2bf(m - bf2f(h));
        c = v.z; s = fmaf(c, c, s); m = -2.f * c; h = f2bf(m);
        hb[q*4+2] = h; lb[q*4+2] = f2bf(m - bf2f(h));
        c = v.w; s = fmaf(c, c, s); m = -2.f * c; h = f2bf(m);
        hb[q*4+3] = h; lb[q*4+3] = f2bf(m - bf2f(h));
    }
    s += __shfl_xor(s, 1);
    s += __shfl_xor(s, 2);
    if (part == 0) csq[row] = s;

    const size_t off = (size_t)row * DDIM + part * 16;
    short4* dh = (short4*)(mh + off);
    short4* dl = (short4*)(ml + off);
#pragma unroll
    for (int q = 0; q < 4; ++q) {
        short4 hv, lv;
        hv.x = (short)hb[q*4+0]; hv.y = (short)hb[q*4+1];
        hv.z = (short)hb[q*4+2]; hv.w = (short)hb[q*4+3];
        lv.x = (short)lb[q*4+0]; lv.y = (short)lb[q*4+1];
        lv.z = (short)lb[q*4+2]; lv.w = (short)lb[q*4+3];
        dh[q] = hv; dl[q] = lv;
    }
}

__device__ __forceinline__ void cvt8(float4 f0, float4 f1, bf16x8* h, bf16x8* l) {
    bf16x8 hh, ll;
    float fv; unsigned short hb;
    fv = f0.x; hb = f2bf(fv); hh[0] = (short)hb; ll[0] = (short)f2bf(fv - bf2f(hb));
    fv = f0.y; hb = f2bf(fv); hh[1] = (short)hb; ll[1] = (short)f2bf(fv - bf2f(hb));
    fv = f0.z; hb = f2bf(fv); hh[2] = (short)hb; ll[2] = (short)f2bf(fv - bf2f(hb));
    fv = f0.w; hb = f2bf(fv); hh[3] = (short)hb; ll[3] = (short)f2bf(fv - bf2f(hb));
    fv = f1.x; hb = f2bf(fv); hh[4] = (short)hb; ll[4] = (short)f2bf(fv - bf2f(hb));
    fv = f1.y; hb = f2bf(fv); hh[5] = (short)hb; ll[5] = (short)f2bf(fv - bf2f(hb));
    fv = f1.z; hb = f2bf(fv); hh[6] = (short)hb; ll[6] = (short)f2bf(fv - bf2f(hb));
    fv = f1.w; hb = f2bf(fv); hh[7] = (short)hb; ll[7] = (short)f2bf(fv - bf2f(hb));
    *h = hh; *l = ll;
}

__global__ __launch_bounds__(256, 3)
void codebook_mfma(const float* __restrict__ x,
                   const float* __restrict__ cb,
                   const unsigned short* __restrict__ cbh,   // bf16 hi of -2c
                   const unsigned short* __restrict__ cbl,   // bf16 lo of -2c
                   const float* __restrict__ csq,
                   float* __restrict__ out_codevec,
                   float* __restrict__ out_codes,
                   float* __restrict__ out_l2) {
    __shared__ float xs[BM][XPAD];     // fp32 x tile (padded), kept for refinement
    __shared__ float xsq_s[BM];
    __shared__ int   cand_s[BM][2];

    const int tid  = threadIdx.x;
    const int lane = tid & 63;
    const int wid  = tid >> 6;
    const int row0 = blockIdx.x * BM;

    // ---- stage x (fp32, coalesced) + per-row ||x||^2 (4 threads/row) ----
    {
        const int r = tid >> 2, p = tid & 3;
        const float4* src = (const float4*)(x + (size_t)(row0 + r) * DDIM + p * 16);
        float4* dst = (float4*)&xs[r][p * 16];
        float s0 = 0.f, s1 = 0.f;
#pragma unroll
        for (int q = 0; q < 4; ++q) {
            float4 v = src[q];
            dst[q] = v;
            s0 = fmaf(v.x, v.x, s0); s0 = fmaf(v.y, v.y, s0);
            s1 = fmaf(v.z, v.z, s1); s1 = fmaf(v.w, v.w, s1);
        }
        float s = s0 + s1;
        s += __shfl_xor(s, 1);
        s += __shfl_xor(s, 2);
        if (p == 0) xsq_s[r] = s;
    }
    __syncthreads();

    const int wrow = wid * 16;     // wave's first row within block (16 rows/wave)
    const int cl   = lane & 15;    // x-row within wave (= D col n)
    const int ch   = lane >> 4;    // k-subgroup (= D row group)

    // ---- x fragments (B operand); row n=cl, k=ks*32+ch*8+j ----
    bf16x8 xh[2], xl[2];
#pragma unroll
    for (int ks = 0; ks < 2; ++ks) {
        const float* p = &xs[wrow + cl][ks * 32 + ch * 8];
        cvt8(*(const float4*)p, *(const float4*)(p + 4), &xh[ks], &xl[ks]);
    }
    const float xq = xsq_s[wrow + cl];

    // per-lane top-2 over this lane's 256-of-1024 cb entries
    float m1 = 3.4e38f, m2 = 3.4e38f;
    int   i1 = 0, i2 = 0;

    const size_t rowbase = (size_t)(row0 + wrow + cl) * KCB;   // this lane's out row

    // ---- K loop: 4 groups x 4 chunks; store burst per group (1KB/row/visit) ----
#pragma unroll
    for (int g = 0; g < 4; ++g) {
        f32x4 acc[4][4];   // [c][nt] -- all indices compile-time (rule #20)

#pragma unroll
        for (int c = 0; c < 4; ++c) {
            const int k0 = (g * 4 + c) << 6;
#pragma unroll
            for (int nt = 0; nt < 4; ++nt) {
                const int ncol = k0 + nt * 16 + cl;       // A row = cb entry
                const size_t bof = (size_t)ncol * DDIM + ch * 8;
                const bf16x8 bh0 = *(const bf16x8*)(cbh + bof);
                const bf16x8 bh1 = *(const bf16x8*)(cbh + bof + 32);
                const bf16x8 bl0 = *(const bf16x8*)(cbl + bof);
                const bf16x8 bl1 = *(const bf16x8*)(cbl + bof + 32);
                const f32x4  cqv = *(const f32x4*)(csq + k0 + nt * 16 + ch * 4);

                // acc init = xsq + csq; MFMA adds -2*dot => acc = l2 directly.
                f32x4 a;
                a[0] = xq + cqv[0]; a[1] = xq + cqv[1];
                a[2] = xq + cqv[2]; a[3] = xq + cqv[3];
                a = __builtin_amdgcn_mfma_f32_16x16x32_bf16(bh0, xh[0], a, 0, 0, 0);
                a = __builtin_amdgcn_mfma_f32_16x16x32_bf16(bh1, xh[1], a, 0, 0, 0);
                a = __builtin_amdgcn_mfma_f32_16x16x32_bf16(bh0, xl[0], a, 0, 0, 0);
                a = __builtin_amdgcn_mfma_f32_16x16x32_bf16(bh1, xl[1], a, 0, 0, 0);
                a = __builtin_amdgcn_mfma_f32_16x16x32_bf16(bl0, xh[0], a, 0, 0, 0);
                a = __builtin_amdgcn_mfma_f32_16x16x32_bf16(bl1, xh[1], a, 0, 0, 0);
                acc[c][nt] = a;

                // per-lane top-2 (indices strictly ascending -> '<' = np.argmin)
                const int idx0 = k0 + nt * 16 + ch * 4;
#pragma unroll
                for (int rg = 0; rg < 4; ++rg) {
                    const float v = a[rg];
                    const int idx = idx0 + rg;
                    const bool c1 = v < m1;
                    const bool c2 = v < m2;
                    const float nm2 = c1 ? m1 : (c2 ? v : m2);
                    const int   ni2 = c1 ? i1 : (c2 ? idx : i2);
                    m2 = nm2; i2 = ni2;
                    m1 = c1 ? v : m1;
                    i1 = c1 ? idx : i1;
                }
            }
        }

        // ---- store burst: each row gets its 1KB (256 cols) in ascending k ----
        // per instr: 16 rows x 64B; 16 consecutive instrs complete 1KB/row.
#pragma unroll
        for (int c = 0; c < 4; ++c)
#pragma unroll
        for (int nt = 0; nt < 4; ++nt) {
            f32x4* dst = (f32x4*)(out_l2 + rowbase + g * 256 + c * 64 + nt * 16 + ch * 4);
            *dst = acc[c][nt];
        }
    }

    // ---- merge top-2 across the 4 lanes sharing each row (masks 16, 32) ----
    {
        float a1 = m1, a2 = m2;
        int   j1 = i1, j2 = i2;
#pragma unroll
        for (int mm = 16; mm <= 32; mm <<= 1) {
            float o1 = __shfl_xor(a1, mm), o2 = __shfl_xor(a2, mm);
            int   q1 = __shfl_xor(j1, mm), q2 = __shfl_xor(j2, mm);
            const bool fw = (o1 < a1) || (o1 == a1 && q1 < j1);
            const float w1 = fw ? o1 : a1; const int wj1 = fw ? q1 : j1;
            const float ca = fw ? a1 : o1; const int cja = fw ? j1 : q1;
            const float cbv = fw ? o2 : a2; const int cjb = fw ? q2 : j2;
            const bool sw = (cbv < ca) || (cbv == ca && cjb < cja);
            a1 = w1; j1 = wj1;
            a2 = sw ? cbv : ca; j2 = sw ? cjb : cja;
        }
        if (ch == 0) {
            cand_s[wrow + cl][0] = j1; cand_s[wrow + cl][1] = j2;
        }
    }
    __syncthreads();

    // ---- fp32 refinement of top-2, codes + code_vec (4 threads/row) ----
    {
        const int r = tid >> 2, p = tid & 3;
        const int half = p & 1;          // 32-float half of the dot
        const int cnd  = p >> 1;         // which candidate
        const int cand = cand_s[r][cnd];
        const float4* xr = (const float4*)&xs[r][half * 32];
        const float4* cr = (const float4*)(cb + (size_t)cand * DDIM + half * 32);
        float s0 = 0.f, s1 = 0.f;
#pragma unroll
        for (int q = 0; q < 4; ++q) {
            float4 xa, ca;
            xa = xr[q];     ca = cr[q];
            s0 = fmaf(xa.x, ca.x, s0); s0 = fmaf(xa.y, ca.y, s0);
            s0 = fmaf(xa.z, ca.z, s0); s0 = fmaf(xa.w, ca.w, s0);
            xa = xr[q + 4]; ca = cr[q + 4];
            s1 = fmaf(xa.x, ca.x, s1); s1 = fmaf(xa.y, ca.y, s1);
            s1 = fmaf(xa.z, ca.z, s1); s1 = fmaf(xa.w, ca.w, s1);
        }
        float dot = s0 + s1;
        dot += __shfl_xor(dot, 1);       // combine halves -> full dot at p=0,2
        const float d = fmaf(-2.f, dot, xsq_s[r] + csq[cand]);
        const float od = __shfl_xor(d, 2);
        const int   oc = __shfl_xor(cand, 2);
        const bool win = (d < od) || (d == od && cand < oc);
        const int w = win ? cand : oc;
        if (p == 0) out_codes[row0 + r] = (float)w;
        // each of the 4 threads copies 16 floats of the winner row
        const float4* wv = (const float4*)(cb + (size_t)w * DDIM + p * 16);
        float4* ov = (float4*)(out_codevec + (size_t)(row0 + r) * DDIM + p * 16);
#pragma unroll
        for (int q = 0; q < 4; ++q) ov[q] = wv[q];
    }
}

extern "C" void kernel_launch(void* const* d_in, const int* in_sizes, int n_in,
                              void* d_out, int out_size, void* d_ws, size_t ws_size,
                              hipStream_t stream) {
    (void)in_sizes; (void)n_in; (void)out_size; (void)ws_size;
    const float* x  = (const float*)d_in[0];
    const float* cb = (const float*)d_in[1];

    unsigned short* cbh = (unsigned short*)d_ws;                 // 128 KB
    unsigned short* cbl = cbh + (size_t)KCB * DDIM;              // 128 KB
    float*          csq = (float*)(cbl + (size_t)KCB * DDIM);    // 4 KB

    float* out_codevec = (float*)d_out;                          // N*D
    float* out_codes   = out_codevec + (size_t)NROWS * DDIM;     // N
    float* out_l2      = out_codes + NROWS;                      // N*K

    convert_cb<<<16, 256, 0, stream>>>(cb, cbh, cbl, csq);
    codebook_mfma<<<NROWS / BM, 256, 0, stream>>>(x, cb, cbh, cbl, csq,
                                                  out_codevec, out_codes, out_l2);
}

// Round 14
// 230.042 us; speedup vs baseline: 1.3430x; 1.3430x over previous
//
#include <hip/hip_runtime.h>
#include <stdint.h>

#define NROWS 131072
#define DDIM  64
#define KCB   1024
#define BM    128          // rows per block (4 waves x 32)
#define NSTEP 32           // K steps of 32 cols
#define XPAD  68           // padded LDS row stride (floats)

typedef short bf16x8 __attribute__((ext_vector_type(8)));
typedef float f32x4  __attribute__((ext_vector_type(4)));

__device__ __forceinline__ unsigned short f2bf(float f) {
    unsigned int u = __float_as_uint(f);
    u += 0x7FFFu + ((u >> 16) & 1u);
    return (unsigned short)(u >> 16);
}
__device__ __forceinline__ float bf2f(unsigned short h) {
    return __uint_as_float(((unsigned int)h) << 16);
}

// ---- pre-kernel: codebook -> bf16 hi/lo planes of (-2*c) + ||c||^2 (fp32) ----
__global__ __launch_bounds__(256)
void convert_cb(const float* __restrict__ cb,
                unsigned short* __restrict__ mh,
                unsigned short* __restrict__ ml,
                float* __restrict__ csq) {
    const int t    = blockIdx.x * 256 + threadIdx.x;   // 0..4095
    const int row  = t >> 2;
    const int part = t & 3;
    const float4* src = (const float4*)(cb + (size_t)row * DDIM + part * 16);

    unsigned short hb[16], lb[16];
    float s = 0.f;
#pragma unroll
    for (int q = 0; q < 4; ++q) {
        float4 v = src[q];
        float c, m; unsigned short h;
        c = v.x; s = fmaf(c, c, s); m = -2.f * c; h = f2bf(m);
        hb[q*4+0] = h; lb[q*4+0] = f2bf(m - bf2f(h));
        c = v.y; s = fmaf(c, c, s); m = -2.f * c; h = f2bf(m);
        hb[q*4+1] = h; lb[q*4+1] = f2bf(m - bf2f(h));
        c = v.z; s = fmaf(c, c, s); m = -2.f * c; h = f2bf(m);
        hb[q*4+2] = h; lb[q*4+2] = f2bf(m - bf2f(h));
        c = v.w; s = fmaf(c, c, s); m = -2.f * c; h = f2bf(m);
        hb[q*4+3] = h; lb[q*4+3] = f2bf(m - bf2f(h));
    }
    s += __shfl_xor(s, 1);
    s += __shfl_xor(s, 2);
    if (part == 0) csq[row] = s;

    const size_t off = (size_t)row * DDIM + part * 16;
    short4* dh = (short4*)(mh + off);
    short4* dl = (short4*)(ml + off);
#pragma unroll
    for (int q = 0; q < 4; ++q) {
        short4 hv, lv;
        hv.x = (short)hb[q*4+0]; hv.y = (short)hb[q*4+1];
        hv.z = (short)hb[q*4+2]; hv.w = (short)hb[q*4+3];
        lv.x = (short)lb[q*4+0]; lv.y = (short)lb[q*4+1];
        lv.z = (short)lb[q*4+2]; lv.w = (short)lb[q*4+3];
        dh[q] = hv; dl[q] = lv;
    }
}

__device__ __forceinline__ void cvt8(float4 f0, float4 f1, bf16x8* h, bf16x8* l) {
    bf16x8 hh, ll;
    float fv; unsigned short hb;
    fv = f0.x; hb = f2bf(fv); hh[0] = (short)hb; ll[0] = (short)f2bf(fv - bf2f(hb));
    fv = f0.y; hb = f2bf(fv); hh[1] = (short)hb; ll[1] = (short)f2bf(fv - bf2f(hb));
    fv = f0.z; hb = f2bf(fv); hh[2] = (short)hb; ll[2] = (short)f2bf(fv - bf2f(hb));
    fv = f0.w; hb = f2bf(fv); hh[3] = (short)hb; ll[3] = (short)f2bf(fv - bf2f(hb));
    fv = f1.x; hb = f2bf(fv); hh[4] = (short)hb; ll[4] = (short)f2bf(fv - bf2f(hb));
    fv = f1.y; hb = f2bf(fv); hh[5] = (short)hb; ll[5] = (short)f2bf(fv - bf2f(hb));
    fv = f1.z; hb = f2bf(fv); hh[6] = (short)hb; ll[6] = (short)f2bf(fv - bf2f(hb));
    fv = f1.w; hb = f2bf(fv); hh[7] = (short)hb; ll[7] = (short)f2bf(fv - bf2f(hb));
    *h = hh; *l = ll;
}

// ---- pipeline stages (forceinline; all reg indices static after inlining) ----
__device__ __forceinline__ void prefetch_step(
        int hh, int cl, int ch,
        const unsigned short* __restrict__ cbh,
        const unsigned short* __restrict__ cbl,
        const float* __restrict__ csq,
        bf16x8 (&bh0)[2], bf16x8 (&bh1)[2],
        bf16x8 (&bl0)[2], bf16x8 (&bl1)[2], f32x4 (&cq)[2]) {
#pragma unroll
    for (int nt2 = 0; nt2 < 2; ++nt2) {
        const int ncol = hh * 32 + nt2 * 16 + cl;
        const size_t bof = (size_t)ncol * DDIM + ch * 8;
        bh0[nt2] = *(const bf16x8*)(cbh + bof);
        bh1[nt2] = *(const bf16x8*)(cbh + bof + 32);
        bl0[nt2] = *(const bf16x8*)(cbl + bof);
        bl1[nt2] = *(const bf16x8*)(cbl + bof + 32);
        cq[nt2]  = *(const f32x4*)(csq + hh * 32 + nt2 * 16 + ch * 4);
    }
}

__device__ __forceinline__ void compute_step(
        int hh, int cl, int ch, size_t outbase0, size_t outbase1,
        const bf16x8 (&bh0)[2], const bf16x8 (&bh1)[2],
        const bf16x8 (&bl0)[2], const bf16x8 (&bl1)[2], const f32x4 (&cq)[2],
        const bf16x8 (&xh)[2][2], const bf16x8 (&xl)[2][2], const float (&xq)[2],
        float (&m1)[2], float (&m2)[2], int (&i1)[2], int (&i2)[2],
        float* __restrict__ out_l2) {
#pragma unroll
    for (int nt2 = 0; nt2 < 2; ++nt2) {
#pragma unroll
        for (int mt = 0; mt < 2; ++mt) {
            f32x4 a;
            a[0] = xq[mt] + cq[nt2][0]; a[1] = xq[mt] + cq[nt2][1];
            a[2] = xq[mt] + cq[nt2][2]; a[3] = xq[mt] + cq[nt2][3];
            a = __builtin_amdgcn_mfma_f32_16x16x32_bf16(bh0[nt2], xh[mt][0], a, 0, 0, 0);
            a = __builtin_amdgcn_mfma_f32_16x16x32_bf16(bh1[nt2], xh[mt][1], a, 0, 0, 0);
            a = __builtin_amdgcn_mfma_f32_16x16x32_bf16(bh0[nt2], xl[mt][0], a, 0, 0, 0);
            a = __builtin_amdgcn_mfma_f32_16x16x32_bf16(bh1[nt2], xl[mt][1], a, 0, 0, 0);
            a = __builtin_amdgcn_mfma_f32_16x16x32_bf16(bl0[nt2], xh[mt][0], a, 0, 0, 0);
            a = __builtin_amdgcn_mfma_f32_16x16x32_bf16(bl1[nt2], xh[mt][1], a, 0, 0, 0);

            const int coff = hh * 32 + nt2 * 16 + ch * 4;
            f32x4* dst = (f32x4*)(out_l2 + (mt == 0 ? outbase0 : outbase1) + coff);
            *dst = a;

            // per-lane top-2 (indices strictly ascending -> '<' = np.argmin)
#pragma unroll
            for (int rg = 0; rg < 4; ++rg) {
                const float v = a[rg];
                const int idx = coff + rg;
                const bool c1 = v < m1[mt];
                const bool c2 = v < m2[mt];
                const float nm2 = c1 ? m1[mt] : (c2 ? v : m2[mt]);
                const int   ni2 = c1 ? i1[mt] : (c2 ? idx : i2[mt]);
                m2[mt] = nm2; i2[mt] = ni2;
                m1[mt] = c1 ? v : m1[mt];
                i1[mt] = c1 ? idx : i1[mt];
            }
        }
    }
}

__global__ __launch_bounds__(256, 3)
void codebook_mfma(const float* __restrict__ x,
                   const float* __restrict__ cb,
                   const unsigned short* __restrict__ cbh,   // bf16 hi of -2c
                   const unsigned short* __restrict__ cbl,   // bf16 lo of -2c
                   const float* __restrict__ csq,
                   float* __restrict__ out_codevec,
                   float* __restrict__ out_codes,
                   float* __restrict__ out_l2) {
    __shared__ float xs[BM][XPAD];     // fp32 x tile (padded), kept for refinement
    __shared__ float xsq_s[BM];
    __shared__ int   cand_s[BM][2];

    const int tid  = threadIdx.x;
    const int lane = tid & 63;
    const int wid  = tid >> 6;
    const int row0 = blockIdx.x * BM;

    // ---- stage x (fp32, coalesced) + per-row ||x||^2 ----
    {
        const int r = tid >> 1, h = tid & 1;
        const float4* src = (const float4*)(x + (size_t)(row0 + r) * DDIM + h * 32);
        float4* dst = (float4*)&xs[r][h * 32];
        float s0 = 0.f, s1 = 0.f;
#pragma unroll
        for (int q = 0; q < 8; ++q) {
            float4 v = src[q];
            dst[q] = v;
            s0 = fmaf(v.x, v.x, s0); s0 = fmaf(v.y, v.y, s0);
            s1 = fmaf(v.z, v.z, s1); s1 = fmaf(v.w, v.w, s1);
        }
        float s = s0 + s1;
        s += __shfl_xor(s, 1);
        if (h == 0) xsq_s[r] = s;
    }
    __syncthreads();

    const int mrow = wid * 32;     // wave's first row within block
    const int cl   = lane & 15;    // x-row within 16-group (= D col n)
    const int ch   = lane >> 4;    // k-subgroup (= D row group)

    // ---- x fragments (B operand); row n=cl, k=ks*32+ch*8+j ----
    bf16x8 xh[2][2], xl[2][2];
#pragma unroll
    for (int mt = 0; mt < 2; ++mt)
#pragma unroll
    for (int ks = 0; ks < 2; ++ks) {
        const float* p = &xs[mrow + mt * 16 + cl][ks * 32 + ch * 8];
        cvt8(*(const float4*)p, *(const float4*)(p + 4), &xh[mt][ks], &xl[mt][ks]);
    }

    float xq[2];
    xq[0] = xsq_s[mrow + cl];
    xq[1] = xsq_s[mrow + 16 + cl];

    float m1[2], m2[2];
    int   i1[2], i2[2];
#pragma unroll
    for (int mt = 0; mt < 2; ++mt) {
        m1[mt] = 3.4e38f; m2[mt] = 3.4e38f; i1[mt] = 0; i2[mt] = 0;
    }

    const size_t outbase0 = (size_t)(row0 + mrow + cl) * KCB;        // mt=0 row
    const size_t outbase1 = (size_t)(row0 + mrow + 16 + cl) * KCB;   // mt=1 row

    // ---- software-pipelined K loop: PREFETCH(next) issued BEFORE stores(cur)
    // so vmcnt waits for loads never require store drain (in-order counter).
    bf16x8 Abh0[2], Abh1[2], Abl0[2], Abl1[2]; f32x4 Acq[2];
    bf16x8 Bbh0[2], Bbh1[2], Bbl0[2], Bbl1[2]; f32x4 Bcq[2];

    prefetch_step(0, cl, ch, cbh, cbl, csq, Abh0, Abh1, Abl0, Abl1, Acq);

    for (int h = 0; h < NSTEP; h += 2) {
        prefetch_step(h + 1, cl, ch, cbh, cbl, csq, Bbh0, Bbh1, Bbl0, Bbl1, Bcq);
        __builtin_amdgcn_sched_barrier(0);
        compute_step(h, cl, ch, outbase0, outbase1,
                     Abh0, Abh1, Abl0, Abl1, Acq,
                     xh, xl, xq, m1, m2, i1, i2, out_l2);
        __builtin_amdgcn_sched_barrier(0);
        if (h + 2 < NSTEP)
            prefetch_step(h + 2, cl, ch, cbh, cbl, csq, Abh0, Abh1, Abl0, Abl1, Acq);
        __builtin_amdgcn_sched_barrier(0);
        compute_step(h + 1, cl, ch, outbase0, outbase1,
                     Bbh0, Bbh1, Bbl0, Bbl1, Bcq,
                     xh, xl, xq, m1, m2, i1, i2, out_l2);
        __builtin_amdgcn_sched_barrier(0);
    }

    // ---- merge top-2 across the 4 lanes sharing each row (masks 16, 32) ----
#pragma unroll
    for (int mt = 0; mt < 2; ++mt) {
        float a1 = m1[mt], a2 = m2[mt];
        int   j1 = i1[mt], j2 = i2[mt];
#pragma unroll
        for (int mm = 16; mm <= 32; mm <<= 1) {
            float o1 = __shfl_xor(a1, mm), o2 = __shfl_xor(a2, mm);
            int   q1 = __shfl_xor(j1, mm), q2 = __shfl_xor(j2, mm);
            const bool fw = (o1 < a1) || (o1 == a1 && q1 < j1);
            const float w1 = fw ? o1 : a1; const int wj1 = fw ? q1 : j1;
            const float ca = fw ? a1 : o1; const int cja = fw ? j1 : q1;
            const float cbv = fw ? o2 : a2; const int cjb = fw ? q2 : j2;
            const bool sw = (cbv < ca) || (cbv == ca && cjb < cja);
            a1 = w1; j1 = wj1;
            a2 = sw ? cbv : ca; j2 = sw ? cjb : cja;
        }
        if (ch == 0) {
            const int r = mrow + mt * 16 + cl;
            cand_s[r][0] = j1; cand_s[r][1] = j2;
        }
    }
    __syncthreads();

    // ---- fp32 refinement of top-2, codes + code_vec ----
    {
        const int r = tid >> 1, h = tid & 1;
        const int cand = cand_s[r][h];
        const float4* xr = (const float4*)&xs[r][0];
        const float4* cr = (const float4*)(cb + (size_t)cand * DDIM);
        float s0 = 0.f, s1 = 0.f, s2 = 0.f, s3 = 0.f;
#pragma unroll
        for (int q = 0; q < 4; ++q) {
            float4 xa, ca;
            xa = xr[q];      ca = cr[q];
            s0 = fmaf(xa.x, ca.x, s0); s0 = fmaf(xa.y, ca.y, s0);
            s0 = fmaf(xa.z, ca.z, s0); s0 = fmaf(xa.w, ca.w, s0);
            xa = xr[q + 4];  ca = cr[q + 4];
            s1 = fmaf(xa.x, ca.x, s1); s1 = fmaf(xa.y, ca.y, s1);
            s1 = fmaf(xa.z, ca.z, s1); s1 = fmaf(xa.w, ca.w, s1);
            xa = xr[q + 8];  ca = cr[q + 8];
            s2 = fmaf(xa.x, ca.x, s2); s2 = fmaf(xa.y, ca.y, s2);
            s2 = fmaf(xa.z, ca.z, s2); s2 = fmaf(xa.w, ca.w, s2);
            xa = xr[q + 12]; ca = cr[q + 12];
            s3 = fmaf(xa.x, ca.x, s3); s3 = fmaf(xa.y, ca.y, s3);
            s3 = fmaf(xa.z, ca.z, s3); s3 = fmaf(xa.w, ca.w, s3);
        }
        const float dot = (s0 + s1) + (s2 + s3);
        const float d = fmaf(-2.f, dot, xsq_s[r] + csq[cand]);
        const float od = __shfl_xor(d, 1);
        const int   oc = __shfl_xor(cand, 1);
        const bool win = (d < od) || (d == od && cand < oc);
        const int w = win ? cand : oc;
        if (h == 0) out_codes[row0 + r] = (float)w;
        const float4* wv = (const float4*)(cb + (size_t)w * DDIM + h * 32);
        float4* ov = (float4*)(out_codevec + (size_t)(row0 + r) * DDIM + h * 32);
#pragma unroll
        for (int q = 0; q < 8; ++q) ov[q] = wv[q];
    }
}

extern "C" void kernel_launch(void* const* d_in, const int* in_sizes, int n_in,
                              void* d_out, int out_size, void* d_ws, size_t ws_size,
                              hipStream_t stream) {
    (void)in_sizes; (void)n_in; (void)out_size; (void)ws_size;
    const float* x  = (const float*)d_in[0];
    const float* cb = (const float*)d_in[1];

    unsigned short* cbh = (unsigned short*)d_ws;                 // 128 KB
    unsigned short* cbl = cbh + (size_t)KCB * DDIM;              // 128 KB
    float*          csq = (float*)(cbl + (size_t)KCB * DDIM);    // 4 KB

    float* out_codevec = (float*)d_out;                          // N*D
    float* out_codes   = out_codevec + (size_t)NROWS * DDIM;     // N
    float* out_l2      = out_codes + NROWS;                      // N*K

    convert_cb<<<16, 256, 0, stream>>>(cb, cbh, cbl, csq);
    codebook_mfma<<<NROWS / BM, 256, 0, stream>>>(x, cb, cbh, cbl, csq,
                                                  out_codevec, out_codes, out_l2);
}